// Round 6
// baseline (411.108 us; speedup 1.0000x reference)
//
#include <hip/hip_runtime.h>

#define CDIM 768
#define SDIM 4096

typedef float nfloat4 __attribute__((ext_vector_type(4))); // native vec for nontemporal builtin

// out[b,c] = bias[c] + sum_k X[b,k] * W[c,k]   (one wave per output element)
__global__ __launch_bounds__(256) void small_gemm_kernel(
    const float* __restrict__ X, const float* __restrict__ W,
    const float* __restrict__ bias, float* __restrict__ out,
    int Cn, int K)
{
    int gid  = blockIdx.x * blockDim.x + threadIdx.x;
    int wid  = gid >> 6;
    int lane = threadIdx.x & 63;
    int total = 16 * Cn;
    if (wid >= total) return;
    int b = wid / Cn;
    int c = wid - b * Cn;
    const float* x = X + (size_t)b * K;
    const float* w = W + (size_t)c * K;
    float acc = 0.f;
    for (int k = lane * 4; k < K; k += 256) {
        float4 xv = *(const float4*)(x + k);
        float4 wv = *(const float4*)(w + k);
        acc += xv.x * wv.x + xv.y * wv.y + xv.z * wv.z + xv.w * wv.w;
    }
#pragma unroll
    for (int m = 32; m; m >>= 1) acc += __shfl_xor(acc, m, 64);
    if (lane == 0) out[wid] = acc + bias[c];
}

// Pass 1: partial A = sum_c (sp+p), B = sum_c (sp+p)^2 over a 384-c chunk.
// grid (SDIM/256, 16, 2), block 256 = 4 waves. Tile = (b, 256-s, 384-c half).
// Lane owns 4 CONSECUTIVE s (float4): every wave-load is 1KB fully contiguous
// (16B/lane x 64 — the coalescing sweet spot; was 512B float2 in R4/R5).
// Wave w accumulates 96 rows; no cross-lane reduction; 4-wave LDS combine.
__global__ __launch_bounds__(256) void ln_stats(
    const float* __restrict__ sp, const float* __restrict__ proj,
    float* __restrict__ Aout, float* __restrict__ Bout)
{
    __shared__ float s_proj[CDIM / 2];
    __shared__ float4 redA[4][64];
    __shared__ float4 redB[4][64];
    const int b  = blockIdx.y;
    const int s0 = blockIdx.x * 256;
    const int z  = blockIdx.z;
    const int t  = threadIdx.x;
    for (int i = t; i < CDIM / 2; i += 256) s_proj[i] = proj[b * CDIM + z * (CDIM / 2) + i];
    __syncthreads();

    const int lane = t & 63;
    const int wave = t >> 6;
    const float4* base = (const float4*)(sp + (size_t)b * CDIM * SDIM
                                            + (size_t)z * (CDIM / 2) * SDIM + s0) + lane;

    float4 A = make_float4(0.f, 0.f, 0.f, 0.f);
    float4 B = make_float4(0.f, 0.f, 0.f, 0.f);
    const int lc0 = wave * 96;            // 96 local c-rows per wave
    for (int lc = lc0; lc < lc0 + 96; lc += 8) {
        float4 v[8];
#pragma unroll
        for (int k = 0; k < 8; ++k) v[k] = base[(size_t)(lc + k) * (SDIM / 4)];
#pragma unroll
        for (int k = 0; k < 8; ++k) {
            float p = s_proj[lc + k];
            float ax = v[k].x + p, ay = v[k].y + p, az = v[k].z + p, aw = v[k].w + p;
            A.x += ax;      A.y += ay;      A.z += az;      A.w += aw;
            B.x += ax * ax; B.y += ay * ay; B.z += az * az; B.w += aw * aw;
        }
    }
    redA[wave][lane] = A;
    redB[wave][lane] = B;
    __syncthreads();

    if (t < 64) {
        float4 a = redA[0][t], bb = redB[0][t];
#pragma unroll
        for (int w = 1; w < 4; ++w) {
            a.x  += redA[w][t].x;  a.y  += redA[w][t].y;
            a.z  += redA[w][t].z;  a.w  += redA[w][t].w;
            bb.x += redB[w][t].x;  bb.y += redB[w][t].y;
            bb.z += redB[w][t].z;  bb.w += redB[w][t].w;
        }
        ((float4*)(Aout + ((size_t)z * 16 + b) * SDIM + s0))[t] = a;
        ((float4*)(Bout + ((size_t)z * 16 + b) * SDIM + s0))[t] = bb;
    }
}

// Pass 2: normalize + write. grid (SDIM/256, 16, 4), block 256 = 4 waves.
// Tile = (b, 256-s, 192-c quarter). Lane owns 4 consecutive s; mu/rs in
// registers (float4). Per row: 1KB contiguous wave-load of sp (L3-warm from
// pass 1 if retained), FMA, 1KB contiguous NONTEMPORAL wave-store (bypasses
// L3 so sp stays resident for our own later reads).
__global__ __launch_bounds__(256) void ln_norm(
    const float* __restrict__ sp, const float* __restrict__ proj,
    const float* __restrict__ Ain, const float* __restrict__ Bin,
    const float* __restrict__ gamma, const float* __restrict__ beta,
    float* __restrict__ out)
{
    __shared__ float s_p[CDIM / 4], s_g[CDIM / 4], s_b[CDIM / 4];
    const int b      = blockIdx.y;
    const int s0     = blockIdx.x * 256;
    const int c_base = blockIdx.z * (CDIM / 4);   // 192 c's per block
    const int t      = threadIdx.x;
    if (t < CDIM / 4) {
        s_p[t] = proj[b * CDIM + c_base + t];
        s_g[t] = gamma[c_base + t];
        s_b[t] = beta[c_base + t];
    }
    __syncthreads();

    const int lane = t & 63;
    const int wave = t >> 6;

    float4 a0 = ((const float4*)(Ain + ((size_t)0 * 16 + b) * SDIM + s0))[lane];
    float4 a1 = ((const float4*)(Ain + ((size_t)1 * 16 + b) * SDIM + s0))[lane];
    float4 b0 = ((const float4*)(Bin + ((size_t)0 * 16 + b) * SDIM + s0))[lane];
    float4 b1 = ((const float4*)(Bin + ((size_t)1 * 16 + b) * SDIM + s0))[lane];
    const float inv = 1.f / CDIM;
    float4 mu, rs;
    mu.x = (a0.x + a1.x) * inv; mu.y = (a0.y + a1.y) * inv;
    mu.z = (a0.z + a1.z) * inv; mu.w = (a0.w + a1.w) * inv;
    rs.x = rsqrtf((b0.x + b1.x) * inv - mu.x * mu.x + 1e-5f);
    rs.y = rsqrtf((b0.y + b1.y) * inv - mu.y * mu.y + 1e-5f);
    rs.z = rsqrtf((b0.z + b1.z) * inv - mu.z * mu.z + 1e-5f);
    rs.w = rsqrtf((b0.w + b1.w) * inv - mu.w * mu.w + 1e-5f);

    const float4* spv  = (const float4*)(sp  + (size_t)b * CDIM * SDIM
                                             + (size_t)c_base * SDIM + s0) + lane;
    nfloat4*      outv = (nfloat4*)     (out + (size_t)b * CDIM * SDIM
                                             + (size_t)c_base * SDIM + s0) + lane;

    const int rbeg = wave * 48;   // 48 rows per wave
    for (int r = rbeg; r < rbeg + 48; r += 8) {
        float4 v[8];
#pragma unroll
        for (int k = 0; k < 8; ++k)
            v[k] = spv[(size_t)(r + k) * (SDIM / 4)];
#pragma unroll
        for (int k = 0; k < 8; ++k) {
            float p  = s_p[r + k];
            float g  = s_g[r + k];
            float be = s_b[r + k];
            nfloat4 y;
            y.x = (v[k].x + p - mu.x) * (rs.x * g) + be;
            y.y = (v[k].y + p - mu.y) * (rs.y * g) + be;
            y.z = (v[k].z + p - mu.z) * (rs.z * g) + be;
            y.w = (v[k].w + p - mu.w) * (rs.w * g) + be;
            __builtin_nontemporal_store(y, &outv[(size_t)(r + k) * (SDIM / 4)]);
        }
    }
}

extern "C" void kernel_launch(void* const* d_in, const int* in_sizes, int n_in,
                              void* d_out, int out_size, void* d_ws, size_t ws_size,
                              hipStream_t stream) {
    const float* sp           = (const float*)d_in[0];
    const float* conditioning = (const float*)d_in[1];
    const float* w_cond       = (const float*)d_in[2];
    const float* b_cond       = (const float*)d_in[3];
    const float* in_proj_w    = (const float*)d_in[4];
    const float* in_proj_b    = (const float*)d_in[5];
    const float* attn_out_w   = (const float*)d_in[6];
    const float* attn_out_b   = (const float*)d_in[7];
    const float* w_out        = (const float*)d_in[8];
    const float* b_out        = (const float*)d_in[9];
    const float* ln_gamma     = (const float*)d_in[10];
    const float* ln_beta      = (const float*)d_in[11];
    float* out = (float*)d_out;
    float* ws  = (float*)d_ws;

    float* cond = ws;            // 16*768
    float* v    = ws + 12288;    // 16*768
    float* attn = ws + 24576;    // 16*768
    float* proj = ws + 36864;    // 16*768
    float* Ast  = ws + 49152;    // 2*16*4096 (two z-partial planes)
    float* Bst  = ws + 180224;   // 2*16*4096   (ws total: 311296 floats = 1.2MB)

    const int gemm_blocks = (16 * CDIM) / 4; // 4 waves/block, one wave per output
    small_gemm_kernel<<<gemm_blocks, 256, 0, stream>>>(
        conditioning, w_cond, b_cond, cond, CDIM, 1024);
    small_gemm_kernel<<<gemm_blocks, 256, 0, stream>>>(
        cond, in_proj_w + 2 * CDIM * CDIM, in_proj_b + 2 * CDIM, v, CDIM, CDIM);
    small_gemm_kernel<<<gemm_blocks, 256, 0, stream>>>(
        v, attn_out_w, attn_out_b, attn, CDIM, CDIM);
    small_gemm_kernel<<<gemm_blocks, 256, 0, stream>>>(
        attn, w_out, b_out, proj, CDIM, CDIM);

    ln_stats<<<dim3(SDIM / 256, 16, 2), 256, 0, stream>>>(sp, proj, Ast, Bst);
    ln_norm<<<dim3(SDIM / 256, 16, 4), 256, 0, stream>>>(
        sp, proj, Ast, Bst, ln_gamma, ln_beta, out);
}